// Round 3
// baseline (491.604 us; speedup 1.0000x reference)
//
#include <hip/hip_runtime.h>

// ---------------------------------------------------------------------------
// GraphAttention fused kernels for MI355X (gfx950). fp32 I/O.
// Pipeline: memset(stats) -> stats -> prep(BN-folded weight frags + qkv bias)
//           -> main (persistent blocks: x->bf16, QKV mfma, attention, out mfma)
// BN fold: y@W = x@(scale*W) + (shift@W)  => main never needs scale/shift.
// R5: persistent main (512 blocks x 16 chunks), weights held in VGPRs across
//     chunks, x prefetched one chunk ahead into registers, non-temporal direct
//     stores (no phase-4, no RFO / cache pollution). LDS 48.1KB, VGPR<=128.
// ---------------------------------------------------------------------------

#define VNODES 10
#define CH 128
#define ROWS_TOTAL 327680      // 64*512*10
#define G 4                    // batch items per main block chunk
#define MROWS 40               // rows per chunk
#define MT 3                   // 16-row m-tiles (48 rows; 40-47 zero pad)
#define SX 136                 // LDS row stride (bf16 elems), 272B
#define NCHUNK 8192
#define GRID 512               // 8192 = 512 * 16 exactly

typedef __bf16 bf16x8 __attribute__((ext_vector_type(8)));
typedef __bf16 bf16x2 __attribute__((ext_vector_type(2)));
typedef float f32x4 __attribute__((ext_vector_type(4)));
typedef float f32x2 __attribute__((ext_vector_type(2)));
typedef unsigned u32x4 __attribute__((ext_vector_type(4)));
typedef unsigned u32x2 __attribute__((ext_vector_type(2)));

__device__ __forceinline__ unsigned short f2bfu(float f) {
    __bf16 h = (__bf16)f;
    return __builtin_bit_cast(unsigned short, h);
}
__device__ __forceinline__ unsigned packcvt(float a, float b) {
    bf16x2 t;
    t[0] = (__bf16)a;
    t[1] = (__bf16)b;
    return __builtin_bit_cast(unsigned, t);
}
__device__ __forceinline__ f32x2 up2(unsigned u) {
    f32x2 r;
    r[0] = __uint_as_float(u << 16);
    r[1] = __uint_as_float(u & 0xffff0000u);
    return r;
}

// ---------------------------------------------------------------------------
// BN statistics: per-channel sum / sumsq. 2048 blocks x 256 thr, 160 rows each.
// ---------------------------------------------------------------------------
__global__ __launch_bounds__(256) void stats_kernel(
        const float* __restrict__ x,
        float* __restrict__ ws_sum, float* __restrict__ ws_sq) {
    __shared__ float lsum[8][128];
    __shared__ float lsq[8][128];
    int t = threadIdx.x;
    int slot = t >> 5, g = t & 31;
    float s[4], q[4];
#pragma unroll
    for (int k = 0; k < 4; ++k) { s[k] = 0.f; q[k] = 0.f; }
    size_t base_row = (size_t)blockIdx.x * 160;
    for (int p = 0; p < 20; ++p) {
        size_t row = base_row + p * 8 + slot;
        f32x4 v = *(const f32x4*)(x + row * CH + g * 4);
#pragma unroll
        for (int k = 0; k < 4; ++k) {
            s[k] += v[k];
            q[k] = fmaf(v[k], v[k], q[k]);
        }
    }
#pragma unroll
    for (int k = 0; k < 4; ++k) { lsum[slot][g * 4 + k] = s[k]; lsq[slot][g * 4 + k] = q[k]; }
    __syncthreads();
    if (t < 128) {
        float ts = 0.f, tq = 0.f;
#pragma unroll
        for (int sl = 0; sl < 8; ++sl) { ts += lsum[sl][t]; tq += lsq[sl][t]; }
        atomicAdd(&ws_sum[t], ts);
        atomicAdd(&ws_sq[t], tq);
    }
}

// ---------------------------------------------------------------------------
// Weight prep (AFTER stats): BN-folded MFMA B-fragments + qkv bias vector.
// frag[nt][kt][lane][j] = scale[k]*W[k][nt*16+(lane&15)], k=kt*32+(lane>>4)*8+j
// bq[n] = sum_c shift[c]*W[c][n]
// ---------------------------------------------------------------------------
__global__ __launch_bounds__(256) void prep_kernel(
        const float* __restrict__ wqkv, const float* __restrict__ wout,
        const float* __restrict__ gamma, const float* __restrict__ beta,
        const float* __restrict__ stats,
        unsigned short* __restrict__ fq, unsigned short* __restrict__ fo,
        float* __restrict__ bq) {
    __shared__ float sh_s[128];
    if (blockIdx.x < 32) {
        int tid = blockIdx.x * 256 + threadIdx.x;
        if (tid < 24 * 4 * 64) {                    // w_qkv frags (BN-scaled)
            int l = tid & 63;
            int kt = (tid >> 6) & 3;
            int nt = tid >> 8;
            int quad = l >> 4, n = l & 15;
#pragma unroll
            for (int j = 0; j < 8; ++j) {
                int k = kt * 32 + quad * 8 + j;
                float mean = stats[k] * (1.0f / ROWS_TOTAL);
                float var = stats[128 + k] * (1.0f / ROWS_TOTAL) - mean * mean;
                float sc = gamma[k] * rsqrtf(var + 1e-5f);
                fq[tid * 8 + j] = f2bfu(sc * wqkv[k * 384 + nt * 16 + n]);
            }
        } else if (tid < 24 * 4 * 64 + 8 * 4 * 64) { // w_out frags
            int u = tid - 24 * 4 * 64;
            int l = u & 63;
            int kt = (u >> 6) & 3;
            int nt = u >> 8;
            int quad = l >> 4, n = l & 15;
#pragma unroll
            for (int j = 0; j < 8; ++j) {
                int k = kt * 32 + quad * 8 + j;
                fo[u * 8 + j] = f2bfu(wout[k * 128 + nt * 16 + n]);
            }
        }
    } else {                                        // block 32: qkv bias
        int t = threadIdx.x;
        if (t < 128) {
            float mean = stats[t] * (1.0f / ROWS_TOTAL);
            float var = stats[128 + t] * (1.0f / ROWS_TOTAL) - mean * mean;
            float sc = gamma[t] * rsqrtf(var + 1e-5f);
            sh_s[t] = beta[t] - mean * sc;
        }
        __syncthreads();
        for (int n = t; n < 384; n += 256) {
            float acc = 0.f;
#pragma unroll 8
            for (int c = 0; c < 128; ++c) acc = fmaf(sh_s[c], wqkv[c * 384 + n], acc);
            bq[n] = acc;
        }
    }
}

// ---------------------------------------------------------------------------
// Main fused kernel: 512 thr (8 waves), 512 persistent blocks x 16 chunks.
// LDS 48,144 B; VGPR cap 128 -> 2 blocks/CU (16 waves).
// ---------------------------------------------------------------------------
__global__ __launch_bounds__(512, 4) void main_kernel(
        const float* __restrict__ x,
        const float* __restrict__ maskp,
        const float* __restrict__ bq,
        const unsigned short* __restrict__ wqkv_f,
        const unsigned short* __restrict__ wout_f,
        const float* __restrict__ b_out,
        float* __restrict__ out) {
    __shared__ __align__(16) unsigned short xT[48 * SX];   // x bf16; later attn-out
    __shared__ __align__(16) unsigned short qT[40 * SX];   // Q bf16 (pre-scaled 0.25)
    __shared__ __align__(16) unsigned short kTb[40 * SX];  // K bf16
    __shared__ __align__(16) unsigned short vTb[40 * SX];  // V bf16
    __shared__ float bq_s[384], bout_s[128], mask_s[VNODES * VNODES];

    int tid = threadIdx.x;
    int lane = tid & 63, w = tid >> 6;
    int l15 = lane & 15, quad = lane >> 4;
    int col = w * 16 + l15;

    // ---- once: constants into LDS; zero xT pad rows ----
    if (tid < 384) bq_s[tid] = bq[tid];
    else bout_s[tid - 384] = b_out[tid - 384];
    if (tid < VNODES * VNODES) mask_s[tid] = maskp[tid];
    {   // zero garbage rows 40-47 of xT (finite values for MFMA)
        int r = 40 + (tid >> 6), c = (tid & 63) * 2;
        *(unsigned*)(xT + r * SX + c) = 0u;
    }

    // ---- once: weight fragments into VGPRs ----
    bf16x8 wq[3][4];   // 48 VGPR: nt = {w, w+8, w+16} for Q/K/V
#pragma unroll
    for (int ni = 0; ni < 3; ++ni)
#pragma unroll
        for (int kt = 0; kt < 4; ++kt)
            wq[ni][kt] = *(const bf16x8*)(wqkv_f + (((w + ni * 8) * 4 + kt) * 64 + lane) * 8);
    bf16x8 wo[4];      // 16 VGPR
#pragma unroll
    for (int kt = 0; kt < 4; ++kt)
        wo[kt] = *(const bf16x8*)(wout_f + ((w * 4 + kt) * 64 + lane) * 8);

    __syncthreads();   // bq_s/bout_s visible
    // per-thread loop-invariant bias values (0.25 Q-scale folded into bias too)
    float bqq4 = bq_s[col] * 0.25f;
    float bqk = bq_s[128 + col], bqv = bq_s[256 + col];
    float bias = bout_s[col];

    // ---- prefetch chunk 0 ----
    int c = blockIdx.x;
    f32x4 pf0, pf1, pf2;
    {
        const float* xb = x + (size_t)c * (MROWS * CH);
        pf0 = *(const f32x4*)(xb + tid * 4);
        pf1 = *(const f32x4*)(xb + 2048 + tid * 4);
        if (tid < 256) pf2 = *(const f32x4*)(xb + 4096 + tid * 4);
    }

    while (true) {
        size_t row0 = (size_t)c * MROWS;

        // ---- phase A: prefetched x -> bf16 xT ----
        {
            int r = tid >> 5, g = tid & 31;
            u32x2 t0; t0[0] = packcvt(pf0[0], pf0[1]); t0[1] = packcvt(pf0[2], pf0[3]);
            *(u32x2*)(xT + r * SX + g * 4) = t0;
            u32x2 t1; t1[0] = packcvt(pf1[0], pf1[1]); t1[1] = packcvt(pf1[2], pf1[3]);
            *(u32x2*)(xT + (r + 16) * SX + g * 4) = t1;
            if (tid < 256) {
                u32x2 t2; t2[0] = packcvt(pf2[0], pf2[1]); t2[1] = packcvt(pf2[2], pf2[3]);
                *(u32x2*)(xT + (r + 32) * SX + g * 4) = t2;
            }
        }
        __syncthreads();

        // ---- issue prefetch for next chunk (hides under phases 2-3) ----
        int cn = c + GRID;
        bool more = cn < NCHUNK;
        if (more) {
            const float* xb = x + (size_t)cn * (MROWS * CH);
            pf0 = *(const f32x4*)(xb + tid * 4);
            pf1 = *(const f32x4*)(xb + 2048 + tid * 4);
            if (tid < 256) pf2 = *(const f32x4*)(xb + 4096 + tid * 4);
        }

        // ---- phase 2: qkv = x @ W' + bq via MFMA ----
        {
            for (int mt = 0; mt < MT; ++mt) {
                bf16x8 a[4];
#pragma unroll
                for (int kt = 0; kt < 4; ++kt)
                    a[kt] = *(const bf16x8*)(xT + (mt * 16 + l15) * SX + kt * 32 + quad * 8);
                f32x4 accq = {0.f,0.f,0.f,0.f}, acck = {0.f,0.f,0.f,0.f}, accv = {0.f,0.f,0.f,0.f};
#pragma unroll
                for (int kt = 0; kt < 4; ++kt) {
                    accq = __builtin_amdgcn_mfma_f32_16x16x32_bf16(a[kt], wq[0][kt], accq, 0, 0, 0);
                    acck = __builtin_amdgcn_mfma_f32_16x16x32_bf16(a[kt], wq[1][kt], acck, 0, 0, 0);
                    accv = __builtin_amdgcn_mfma_f32_16x16x32_bf16(a[kt], wq[2][kt], accv, 0, 0, 0);
                }
#pragma unroll
                for (int i = 0; i < 4; ++i) {
                    int rr = mt * 16 + quad * 4 + i;
                    if (rr < MROWS) {
                        qT[rr * SX + col]  = f2bfu(fmaf(accq[i], 0.25f, bqq4));
                        kTb[rr * SX + col] = f2bfu(acck[i] + bqk);
                        vTb[rr * SX + col] = f2bfu(accv[i] + bqv);
                    }
                }
            }
        }
        __syncthreads();

        // ---- phase 2b: masked attention, packed f32 over bf16 K/V; 320 tasks ----
        if (tid < G * 8 * VNODES) {
            int h = tid / (G * VNODES);
            int rem = tid - h * (G * VNODES);
            int b = rem / VNODES;
            int i = rem - b * VNODES;
            int rowi = b * VNODES + i;
            const unsigned* qp = (const unsigned*)(qT + rowi * SX + h * 16);
            u32x4 qw0 = *(const u32x4*)qp;
            u32x4 qw1 = *(const u32x4*)(qp + 4);
            f32x2 qv[8];
#pragma unroll
            for (int d = 0; d < 4; ++d) {
                qv[d]     = up2(qw0[d]);
                qv[4 + d] = up2(qw1[d]);
            }
            float p[VNODES];
            float mx = -1e30f;
#pragma unroll
            for (int j = 0; j < VNODES; ++j) {
                const unsigned* kp = (const unsigned*)(kTb + (b * VNODES + j) * SX + h * 16);
                u32x4 k0 = *(const u32x4*)kp;
                u32x4 k1 = *(const u32x4*)(kp + 4);
                f32x2 acc2 = {0.f, 0.f};
#pragma unroll
                for (int d = 0; d < 4; ++d) {
                    acc2 = __builtin_elementwise_fma(qv[d],     up2(k0[d]), acc2);
                    acc2 = __builtin_elementwise_fma(qv[4 + d], up2(k1[d]), acc2);
                }
                p[j] = (acc2[0] + acc2[1]) * mask_s[i * VNODES + j];
                mx = fmaxf(mx, p[j]);
            }
            float s = 0.f;
#pragma unroll
            for (int j = 0; j < VNODES; ++j) { p[j] = __expf(p[j] - mx); s += p[j]; }
            float inv = 1.0f / s;
            f32x2 o2[8];
#pragma unroll
            for (int d = 0; d < 8; ++d) o2[d] = (f32x2){0.f, 0.f};
#pragma unroll
            for (int j = 0; j < VNODES; ++j) {
                const unsigned* vp = (const unsigned*)(vTb + (b * VNODES + j) * SX + h * 16);
                u32x4 v0 = *(const u32x4*)vp;
                u32x4 v1 = *(const u32x4*)(vp + 4);
                f32x2 pp = {p[j], p[j]};
#pragma unroll
                for (int d = 0; d < 4; ++d) {
                    o2[d]     = __builtin_elementwise_fma(pp, up2(v0[d]), o2[d]);
                    o2[4 + d] = __builtin_elementwise_fma(pp, up2(v1[d]), o2[4 + d]);
                }
            }
            f32x2 iv = {inv, inv};
#pragma unroll
            for (int d2 = 0; d2 < 8; ++d2) {
                f32x2 r = o2[d2] * iv;
                *(unsigned*)(xT + rowi * SX + h * 16 + d2 * 2) = packcvt(r[0], r[1]);
            }
        }
        __syncthreads();

        // ---- phase 3: final = attn @ w_out + b_out; NT store direct to global ----
        {
            for (int mt = 0; mt < MT; ++mt) {
                f32x4 acc = {0.f, 0.f, 0.f, 0.f};
#pragma unroll
                for (int kt = 0; kt < 4; ++kt) {
                    bf16x8 a = *(const bf16x8*)(xT + (mt * 16 + l15) * SX + kt * 32 + quad * 8);
                    acc = __builtin_amdgcn_mfma_f32_16x16x32_bf16(a, wo[kt], acc, 0, 0, 0);
                }
#pragma unroll
                for (int i = 0; i < 4; ++i) {
                    int rr = mt * 16 + quad * 4 + i;
                    if (rr < MROWS)
                        __builtin_nontemporal_store(acc[i] + bias,
                                                    out + (row0 + rr) * CH + col);
                }
            }
        }

        if (!more) break;
        __syncthreads();   // protect xT (phase-3 reads) before next phase-A write
        c = cn;
    }
}

extern "C" void kernel_launch(void* const* d_in, const int* in_sizes, int n_in,
                              void* d_out, int out_size, void* d_ws, size_t ws_size,
                              hipStream_t stream) {
    const float* x     = (const float*)d_in[0];
    const float* gamma = (const float*)d_in[1];
    const float* beta  = (const float*)d_in[2];
    const float* wqkv  = (const float*)d_in[3];
    const float* wout  = (const float*)d_in[4];
    const float* bout  = (const float*)d_in[5];
    const float* maskp = (const float*)d_in[6];
    float* out = (float*)d_out;

    char* ws = (char*)d_ws;
    float* ws_stats = (float*)ws;                          // 256 f32 (sum | sumsq)
    float* bq = (float*)(ws + 1024);                       // 384 f32 qkv bias
    unsigned short* fq = (unsigned short*)(ws + 4096);     // 49152 bf16 qkv frags
    unsigned short* fo = (unsigned short*)(ws + 4096 + 98304); // 16384 bf16 out frags

    hipMemsetAsync(ws, 0, 1024, stream);
    stats_kernel<<<2048, 256, 0, stream>>>(x, ws_stats, ws_stats + 128);
    prep_kernel<<<33, 256, 0, stream>>>(wqkv, wout, gamma, beta, ws_stats, fq, fo, bq);
    main_kernel<<<GRID, 512, 0, stream>>>(x, maskp, bq, fq, fo, bout, out);
}

// Round 4
// 402.095 us; speedup vs baseline: 1.2226x; 1.2226x over previous
//
#include <hip/hip_runtime.h>

// ---------------------------------------------------------------------------
// GraphAttention fused kernels for MI355X (gfx950). fp32 I/O.
// Pipeline: memset(32KB) -> stats (replicated atomics) -> prep (replica-reduce
//           + BN-folded weight frags + qkv bias) -> main (R1-best structure)
// BN fold: y@W = x@(scale*W) + (shift@W)  => main never needs scale/shift.
// R6: stats atomics spread over 32 replica arrays (contention 2048->64 per
//     address); prep reduces replicas. Main = R1 structure (direct non-NT
//     stores, lowest HBM traffic) + native cvt_pk + packed-f32 attention.
// ---------------------------------------------------------------------------

#define VNODES 10
#define CH 128
#define ROWS_TOTAL 327680      // 64*512*10
#define G 4                    // batch items per main block
#define MROWS 40               // real rows per block
#define MT 3                   // 16-row m-tiles (48 rows; 40-47 zero pad)
#define SX 136                 // LDS row stride (bf16 elems), 272B
#define REP 32                 // stats replica arrays

typedef __bf16 bf16x8 __attribute__((ext_vector_type(8)));
typedef __bf16 bf16x2 __attribute__((ext_vector_type(2)));
typedef float f32x4 __attribute__((ext_vector_type(4)));
typedef float f32x2 __attribute__((ext_vector_type(2)));
typedef unsigned u32x4 __attribute__((ext_vector_type(4)));
typedef unsigned u32x2 __attribute__((ext_vector_type(2)));

__device__ __forceinline__ unsigned short f2bfu(float f) {
    __bf16 h = (__bf16)f;
    return __builtin_bit_cast(unsigned short, h);
}
__device__ __forceinline__ unsigned packcvt(float a, float b) {
    bf16x2 t;
    t[0] = (__bf16)a;
    t[1] = (__bf16)b;
    return __builtin_bit_cast(unsigned, t);
}
__device__ __forceinline__ f32x2 up2(unsigned u) {
    f32x2 r;
    r[0] = __uint_as_float(u << 16);
    r[1] = __uint_as_float(u & 0xffff0000u);
    return r;
}

// ---------------------------------------------------------------------------
// BN statistics: per-channel sum / sumsq into REP replica arrays.
// 2048 blocks x 256 thr, 160 rows each; replica = bid & (REP-1).
// ---------------------------------------------------------------------------
__global__ __launch_bounds__(256) void stats_kernel(
        const float* __restrict__ x,
        float* __restrict__ ws_rep) {          // [REP][256]: sum | sumsq
    __shared__ float lsum[8][128];
    __shared__ float lsq[8][128];
    int t = threadIdx.x;
    int slot = t >> 5, g = t & 31;
    float s[4], q[4];
#pragma unroll
    for (int k = 0; k < 4; ++k) { s[k] = 0.f; q[k] = 0.f; }
    size_t base_row = (size_t)blockIdx.x * 160;
    for (int p = 0; p < 20; ++p) {
        size_t row = base_row + p * 8 + slot;
        f32x4 v = *(const f32x4*)(x + row * CH + g * 4);
#pragma unroll
        for (int k = 0; k < 4; ++k) {
            s[k] += v[k];
            q[k] = fmaf(v[k], v[k], q[k]);
        }
    }
#pragma unroll
    for (int k = 0; k < 4; ++k) { lsum[slot][g * 4 + k] = s[k]; lsq[slot][g * 4 + k] = q[k]; }
    __syncthreads();
    if (t < 128) {
        float ts = 0.f, tq = 0.f;
#pragma unroll
        for (int sl = 0; sl < 8; ++sl) { ts += lsum[sl][t]; tq += lsq[sl][t]; }
        float* rep = ws_rep + (blockIdx.x & (REP - 1)) * 256;
        atomicAdd(&rep[t], ts);
        atomicAdd(&rep[128 + t], tq);
    }
}

// ---------------------------------------------------------------------------
// Weight prep (AFTER stats): replica-reduce stats, then BN-folded MFMA
// B-fragments + qkv bias vector.
// frag[nt][kt][lane][j] = scale[k]*W[k][nt*16+(lane&15)], k=kt*32+(lane>>4)*8+j
// bq[n] = sum_c shift[c]*W[c][n]
// ---------------------------------------------------------------------------
__global__ __launch_bounds__(256) void prep_kernel(
        const float* __restrict__ wqkv, const float* __restrict__ wout,
        const float* __restrict__ gamma, const float* __restrict__ beta,
        const float* __restrict__ ws_rep,
        unsigned short* __restrict__ fq, unsigned short* __restrict__ fo,
        float* __restrict__ bq) {
    __shared__ float sh_stats[256];    // [0..127]=sum, [128..255]=sumsq
    __shared__ float sh_s[128];        // shift (block 32 only)
    {   // coalesced replica reduction
        int t = threadIdx.x;
        float acc = 0.f;
#pragma unroll
        for (int r = 0; r < REP; ++r) acc += ws_rep[r * 256 + t];
        sh_stats[t] = acc;
    }
    __syncthreads();

    if (blockIdx.x < 32) {
        int tid = blockIdx.x * 256 + threadIdx.x;
        if (tid < 24 * 4 * 64) {                    // w_qkv frags (BN-scaled)
            int l = tid & 63;
            int kt = (tid >> 6) & 3;
            int nt = tid >> 8;
            int quad = l >> 4, n = l & 15;
#pragma unroll
            for (int j = 0; j < 8; ++j) {
                int k = kt * 32 + quad * 8 + j;
                float mean = sh_stats[k] * (1.0f / ROWS_TOTAL);
                float var = sh_stats[128 + k] * (1.0f / ROWS_TOTAL) - mean * mean;
                float sc = gamma[k] * rsqrtf(var + 1e-5f);
                fq[tid * 8 + j] = f2bfu(sc * wqkv[k * 384 + nt * 16 + n]);
            }
        } else if (tid < 24 * 4 * 64 + 8 * 4 * 64) { // w_out frags
            int u = tid - 24 * 4 * 64;
            int l = u & 63;
            int kt = (u >> 6) & 3;
            int nt = u >> 8;
            int quad = l >> 4, n = l & 15;
#pragma unroll
            for (int j = 0; j < 8; ++j) {
                int k = kt * 32 + quad * 8 + j;
                fo[u * 8 + j] = f2bfu(wout[k * 128 + nt * 16 + n]);
            }
        }
    } else {                                        // block 32: qkv bias
        int t = threadIdx.x;
        if (t < 128) {
            float mean = sh_stats[t] * (1.0f / ROWS_TOTAL);
            float var = sh_stats[128 + t] * (1.0f / ROWS_TOTAL) - mean * mean;
            float sc = gamma[t] * rsqrtf(var + 1e-5f);
            sh_s[t] = beta[t] - mean * sc;
        }
        __syncthreads();
        for (int n = t; n < 384; n += 256) {
            float acc = 0.f;
#pragma unroll 8
            for (int c = 0; c < 128; ++c) acc = fmaf(sh_s[c], wqkv[c * 384 + n], acc);
            bq[n] = acc;
        }
    }
}

// ---------------------------------------------------------------------------
// Main fused kernel: 512 thr (8 waves), 8192 blocks, 40 rows (4 batch items).
// LDS 48,144 B -> 3 blocks/CU (24 waves).
// ---------------------------------------------------------------------------
__global__ __launch_bounds__(512, 6) void main_kernel(
        const float* __restrict__ x,
        const float* __restrict__ maskp,
        const float* __restrict__ bq,
        const unsigned short* __restrict__ wqkv_f,
        const unsigned short* __restrict__ wout_f,
        const float* __restrict__ b_out,
        float* __restrict__ out) {
    __shared__ __align__(16) unsigned short xT[48 * SX];   // x bf16; later attn-out
    __shared__ __align__(16) unsigned short qT[40 * SX];   // Q bf16 (pre-scaled 0.25)
    __shared__ __align__(16) unsigned short kTb[40 * SX];  // K bf16
    __shared__ __align__(16) unsigned short vTb[40 * SX];  // V bf16
    __shared__ float bq_s[384], bout_s[128], mask_s[VNODES * VNODES];

    int tid = threadIdx.x;
    int lane = tid & 63, w = tid >> 6;
    size_t row0 = (size_t)blockIdx.x * MROWS;

    // ---- phase 0: constants into LDS; zero xT pad rows ----
    if (tid < 384) bq_s[tid] = bq[tid];
    else bout_s[tid - 384] = b_out[tid - 384];
    if (tid < VNODES * VNODES) mask_s[tid] = maskp[tid];
    {   // zero garbage rows 40-47 of xT (finite values for MFMA)
        int r = 40 + (tid >> 6), c = (tid & 63) * 2;
        *(unsigned*)(xT + r * SX + c) = 0u;
    }

    // ---- phase 1: x (fp32) -> bf16 xT (v_cvt_pk_bf16_f32) ----
    {
#pragma unroll
        for (int p = 0; p < 3; ++p) {
            int idx = p * 512 + tid;              // 1280 f32x4 total
            if (idx < 1280) {
                int r = idx >> 5, g = idx & 31;
                f32x4 v = *(const f32x4*)(x + (row0 + r) * CH + g * 4);
                u32x2 two;
                two[0] = packcvt(v[0], v[1]);
                two[1] = packcvt(v[2], v[3]);
                *(u32x2*)(xT + r * SX + g * 4) = two;
            }
        }
    }
    __syncthreads();

    // ---- phase 2: qkv = x @ W' + bq via MFMA; wave w: nt {w(Q), w+8(K), w+16(V)} ----
    {
        bf16x8 bf[3][4];
#pragma unroll
        for (int ni = 0; ni < 3; ++ni) {
            int nt = w + ni * 8;
#pragma unroll
            for (int kt = 0; kt < 4; ++kt)
                bf[ni][kt] = *(const bf16x8*)(wqkv_f + ((nt * 4 + kt) * 64 + lane) * 8);
        }
        int l15 = lane & 15, quad = lane >> 4;
        for (int mt = 0; mt < MT; ++mt) {
            bf16x8 a[4];
#pragma unroll
            for (int kt = 0; kt < 4; ++kt)
                a[kt] = *(const bf16x8*)(xT + (mt * 16 + l15) * SX + kt * 32 + quad * 8);
            f32x4 accq = {0.f,0.f,0.f,0.f}, acck = {0.f,0.f,0.f,0.f}, accv = {0.f,0.f,0.f,0.f};
#pragma unroll
            for (int kt = 0; kt < 4; ++kt) {
                accq = __builtin_amdgcn_mfma_f32_16x16x32_bf16(a[kt], bf[0][kt], accq, 0, 0, 0);
                acck = __builtin_amdgcn_mfma_f32_16x16x32_bf16(a[kt], bf[1][kt], acck, 0, 0, 0);
                accv = __builtin_amdgcn_mfma_f32_16x16x32_bf16(a[kt], bf[2][kt], accv, 0, 0, 0);
            }
            int col = w * 16 + l15;
            float bqq = bq_s[col], bqk = bq_s[128 + col], bqv = bq_s[256 + col];
#pragma unroll
            for (int i = 0; i < 4; ++i) {
                int rr = mt * 16 + quad * 4 + i;
                if (rr < MROWS) {
                    // Q pre-scaled by DH^-0.5 = 0.25 (exact pow2)
                    qT[rr * SX + col]  = f2bfu((accq[i] + bqq) * 0.25f);
                    kTb[rr * SX + col] = f2bfu(acck[i] + bqk);
                    vTb[rr * SX + col] = f2bfu(accv[i] + bqv);
                }
            }
        }
    }
    __syncthreads();

    // ---- phase 2b: masked attention, packed f32 over bf16 K/V; 320 tasks ----
    if (tid < G * 8 * VNODES) {
        int h = tid / (G * VNODES);
        int rem = tid - h * (G * VNODES);
        int b = rem / VNODES;
        int i = rem - b * VNODES;
        int rowi = b * VNODES + i;
        const unsigned* qp = (const unsigned*)(qT + rowi * SX + h * 16);
        u32x4 qw0 = *(const u32x4*)qp;
        u32x4 qw1 = *(const u32x4*)(qp + 4);
        f32x2 qv[8];
#pragma unroll
        for (int d = 0; d < 4; ++d) {
            qv[d]     = up2(qw0[d]);
            qv[4 + d] = up2(qw1[d]);
        }
        float p[VNODES];
        float mx = -1e30f;
#pragma unroll
        for (int j = 0; j < VNODES; ++j) {
            const unsigned* kp = (const unsigned*)(kTb + (b * VNODES + j) * SX + h * 16);
            u32x4 k0 = *(const u32x4*)kp;
            u32x4 k1 = *(const u32x4*)(kp + 4);
            f32x2 acc2 = {0.f, 0.f};
#pragma unroll
            for (int d = 0; d < 4; ++d) {
                acc2 = __builtin_elementwise_fma(qv[d],     up2(k0[d]), acc2);
                acc2 = __builtin_elementwise_fma(qv[4 + d], up2(k1[d]), acc2);
            }
            p[j] = (acc2[0] + acc2[1]) * mask_s[i * VNODES + j];
            mx = fmaxf(mx, p[j]);
        }
        float s = 0.f;
#pragma unroll
        for (int j = 0; j < VNODES; ++j) { p[j] = __expf(p[j] - mx); s += p[j]; }
        float inv = 1.0f / s;
        f32x2 o2[8];
#pragma unroll
        for (int d = 0; d < 8; ++d) o2[d] = (f32x2){0.f, 0.f};
#pragma unroll
        for (int j = 0; j < VNODES; ++j) {
            const unsigned* vp = (const unsigned*)(vTb + (b * VNODES + j) * SX + h * 16);
            u32x4 v0 = *(const u32x4*)vp;
            u32x4 v1 = *(const u32x4*)(vp + 4);
            f32x2 pp = {p[j], p[j]};
#pragma unroll
            for (int d = 0; d < 4; ++d) {
                o2[d]     = __builtin_elementwise_fma(pp, up2(v0[d]), o2[d]);
                o2[4 + d] = __builtin_elementwise_fma(pp, up2(v1[d]), o2[4 + d]);
            }
        }
        f32x2 iv = {inv, inv};
#pragma unroll
        for (int d2 = 0; d2 < 8; ++d2) {
            f32x2 r = o2[d2] * iv;
            *(unsigned*)(xT + rowi * SX + h * 16 + d2 * 2) = packcvt(r[0], r[1]);
        }
    }
    __syncthreads();

    // ---- phase 3: final = attn @ w_out + b_out; direct store (non-NT) ----
    {
        bf16x8 bfw[4];
#pragma unroll
        for (int kt = 0; kt < 4; ++kt)
            bfw[kt] = *(const bf16x8*)(wout_f + ((w * 4 + kt) * 64 + lane) * 8);
        int l15 = lane & 15, quad = lane >> 4;
        int col = w * 16 + l15;
        float bias = bout_s[col];
        for (int mt = 0; mt < MT; ++mt) {
            f32x4 acc = {0.f, 0.f, 0.f, 0.f};
#pragma unroll
            for (int kt = 0; kt < 4; ++kt) {
                bf16x8 a = *(const bf16x8*)(xT + (mt * 16 + l15) * SX + kt * 32 + quad * 8);
                acc = __builtin_amdgcn_mfma_f32_16x16x32_bf16(a, bfw[kt], acc, 0, 0, 0);
            }
#pragma unroll
            for (int i = 0; i < 4; ++i) {
                int rr = mt * 16 + quad * 4 + i;
                if (rr < MROWS) out[(row0 + rr) * CH + col] = acc[i] + bias;
            }
        }
    }
}

extern "C" void kernel_launch(void* const* d_in, const int* in_sizes, int n_in,
                              void* d_out, int out_size, void* d_ws, size_t ws_size,
                              hipStream_t stream) {
    const float* x     = (const float*)d_in[0];
    const float* gamma = (const float*)d_in[1];
    const float* beta  = (const float*)d_in[2];
    const float* wqkv  = (const float*)d_in[3];
    const float* wout  = (const float*)d_in[4];
    const float* bout  = (const float*)d_in[5];
    const float* maskp = (const float*)d_in[6];
    float* out = (float*)d_out;

    char* ws = (char*)d_ws;
    float* ws_rep = (float*)ws;                            // REP*256 f32 = 32 KB
    float* bq = (float*)(ws + REP * 1024);                 // 384 f32 qkv bias
    unsigned short* fq = (unsigned short*)(ws + REP * 1024 + 4096);      // 49152 bf16
    unsigned short* fo = (unsigned short*)(ws + REP * 1024 + 4096 + 98304); // 16384 bf16

    hipMemsetAsync(ws, 0, REP * 1024, stream);
    stats_kernel<<<2048, 256, 0, stream>>>(x, ws_rep);
    prep_kernel<<<33, 256, 0, stream>>>(wqkv, wout, gamma, beta, ws_rep, fq, fo, bq);
    main_kernel<<<8192, 512, 0, stream>>>(x, maskp, bq, fq, fo, bout, out);
}